// Round 4
// baseline (425.573 us; speedup 1.0000x reference)
//
#include <hip/hip_runtime.h>
#include <hip/hip_bf16.h>

typedef __attribute__((ext_vector_type(4))) float  f32x4;
typedef __attribute__((ext_vector_type(8))) short  bf16x8v;
typedef __attribute__((ext_vector_type(4))) short  bf16x4v;

__device__ __forceinline__ unsigned short f2bf(float x) {
  union { float f; unsigned u; } v; v.f = x;
  unsigned r = v.u + 0x7FFF + ((v.u >> 16) & 1);   // RNE
  return (unsigned short)(r >> 16);
}

constexpr int S  = 2048;
constexpr int D  = 64;
constexpr int BQ = 64;
constexpr int BK = 64;

// One block = 64 q-rows of one (b,h). 4 waves, each owns 16 q-rows.
// LDS: K tile [64][64] bf16 (XOR-swizzled), V^T tile [64][64] bf16
// (XOR-swizzled), per-wave P tile 16x64 bf16.
__global__ __launch_bounds__(256, 4) void attn_fwd(
    const float* __restrict__ Kg, const float* __restrict__ Vg,
    const float* __restrict__ Qg, float* __restrict__ Og) {
  __shared__ unsigned short Kl[BK * D];       // 8 KB
  __shared__ unsigned short Vt[D * BK];       // 8 KB
  __shared__ unsigned short Pl[4 * 16 * BK];  // 8 KB

  const int tid  = threadIdx.x;
  const int lane = tid & 63;
  const int w    = tid >> 6;                 // wave 0..3
  // Longest-job-first: causal work per q-block is (qb+1) k-tiles, so launch
  // heavy q-blocks first to shrink the trailing wave of light blocks.
  const int qb   = 31 - (blockIdx.x & 31);   // 32 q-blocks per (b,h)
  const int bh   = blockIdx.x >> 5;          // 0..63
  const int q0   = qb * BQ;

  const size_t base = (size_t)bh * S * D;
  const float* Kp = Kg + base;
  const float* Vp = Vg + base;
  const float* Qp = Qg + base;
  float*       Op = Og + base;

  const int l15 = lane & 15;
  const int lg  = lane >> 4;           // 0..3

  // ---- Q fragments (MFMA A layout: row = lane&15, k = (lane>>4)*8 + j) ----
  bf16x8v qfrag[2];
  {
    const int qrow = q0 + 16 * w + l15;
    const float* src = Qp + (size_t)qrow * D + lg * 8;
#pragma unroll
    for (int c = 0; c < 2; ++c) {
      f32x4 a = *(const f32x4*)(src + 32 * c);
      f32x4 b = *(const f32x4*)(src + 32 * c + 4);
      bf16x8v f;
      f[0] = f2bf(a[0]); f[1] = f2bf(a[1]); f[2] = f2bf(a[2]); f[3] = f2bf(a[3]);
      f[4] = f2bf(b[0]); f[5] = f2bf(b[1]); f[6] = f2bf(b[2]); f[7] = f2bf(b[3]);
      qfrag[c] = f;
    }
  }

  f32x4 acc[4];
#pragma unroll
  for (int i = 0; i < 4; ++i) acc[i] = (f32x4){0.f, 0.f, 0.f, 0.f};
  float m[4], lsum[4];
#pragma unroll
  for (int r = 0; r < 4; ++r) { m[r] = -INFINITY; lsum[r] = 0.f; }

  const int ktmax = q0 / BK;  // causal: only tiles with keys <= q0+63
  for (int kt = 0; kt <= ktmax; ++kt) {
    __syncthreads();  // previous tile fully consumed before overwrite
    // ---- stage K and V^T tiles (fp32 -> bf16, XOR swizzle) ----
    {
      const int row = tid >> 2;   // 0..63 (key index within tile)
      const int cq  = tid & 3;
      const float* ks = Kp + (size_t)(kt * BK + row) * D;
      const float* vs = Vp + (size_t)(kt * BK + row) * D;
#pragma unroll
      for (int i = 0; i < 4; ++i) {
        const int col = (cq + 4 * i) * 4;  // d offset, float4 aligned
        f32x4 kv = *(const f32x4*)(ks + col);
        bf16x4v kb;
        kb[0] = f2bf(kv[0]); kb[1] = f2bf(kv[1]);
        kb[2] = f2bf(kv[2]); kb[3] = f2bf(kv[3]);
        *(bf16x4v*)((char*)Kl + row * 128 + ((col * 2) ^ ((row & 7) << 4))) = kb;
        f32x4 vv = *(const f32x4*)(vs + col);
#pragma unroll
        for (int j = 0; j < 4; ++j) {
          const int d = col + j;
          *(unsigned short*)((char*)Vt + d * 128 +
                             ((row * 2) ^ ((d & 7) << 4))) = f2bf(vv[j]);
        }
      }
    }
    __syncthreads();

    // ---- S = Q K^T : per-wave 16x64 tile, 8 MFMAs ----
    f32x4 s[4];
#pragma unroll
    for (int n = 0; n < 4; ++n) s[n] = (f32x4){0.f, 0.f, 0.f, 0.f};
#pragma unroll
    for (int n = 0; n < 4; ++n) {
      const int krow = n * 16 + l15;  // B layout: col = lane&15
#pragma unroll
      for (int c = 0; c < 2; ++c) {
        bf16x8v kb = *(const bf16x8v*)((char*)Kl + krow * 128 +
                       (((lg * 16) + 64 * c) ^ ((krow & 7) << 4)));
        s[n] = __builtin_amdgcn_mfma_f32_16x16x32_bf16(qfrag[c], kb, s[n], 0, 0, 0);
      }
    }

    // ---- causal mask + scale (C layout: col=lane&15, row=lg*4+reg) ----
    const int kbase = kt * BK + l15;
    const int qrow4 = q0 + 16 * w + lg * 4;
    float sv[4][4];
#pragma unroll
    for (int n = 0; n < 4; ++n)
#pragma unroll
      for (int r = 0; r < 4; ++r)
        sv[n][r] = (kbase + n * 16 <= qrow4 + r) ? s[n][r] * 0.125f : -INFINITY;

    // ---- online softmax (row-reduce over 16 lanes via shfl_xor) ----
    float pr[4][4];
#pragma unroll
    for (int r = 0; r < 4; ++r) {
      float mx = fmaxf(fmaxf(sv[0][r], sv[1][r]), fmaxf(sv[2][r], sv[3][r]));
      mx = fmaxf(mx, __shfl_xor(mx, 1));
      mx = fmaxf(mx, __shfl_xor(mx, 2));
      mx = fmaxf(mx, __shfl_xor(mx, 4));
      mx = fmaxf(mx, __shfl_xor(mx, 8));
      const float mnew = fmaxf(m[r], mx);
      const float corr = __expf(m[r] - mnew);  // 0 when m was -inf
      m[r] = mnew;
      lsum[r] *= corr;
#pragma unroll
      for (int d = 0; d < 4; ++d) acc[d][r] *= corr;
      float ps = 0.f;
#pragma unroll
      for (int n = 0; n < 4; ++n) {
        const float p = __expf(sv[n][r] - mnew);
        pr[n][r] = p;
        ps += p;
      }
      ps += __shfl_xor(ps, 1);
      ps += __shfl_xor(ps, 2);
      ps += __shfl_xor(ps, 4);
      ps += __shfl_xor(ps, 8);
      lsum[r] += ps;
    }

    // ---- P -> LDS (per-wave region, swizzled) ----
#pragma unroll
    for (int n = 0; n < 4; ++n)
#pragma unroll
      for (int r = 0; r < 4; ++r) {
        const int q  = lg * 4 + r;
        const int k2 = (n * 16 + l15) * 2;
        *(unsigned short*)((char*)Pl + w * 2048 + q * 128 +
                           (k2 ^ ((q & 7) << 4))) = f2bf(pr[n][r]);
      }

    // ---- O += P V : read P as A-frag, V^T as B-frag, 8 MFMAs ----
    bf16x8v pa[2];
#pragma unroll
    for (int c = 0; c < 2; ++c) {
      const int k2 = (lg * 8 + 32 * c) * 2;
      pa[c] = *(const bf16x8v*)((char*)Pl + w * 2048 + l15 * 128 +
                                (k2 ^ ((l15 & 7) << 4)));
    }
#pragma unroll
    for (int dsub = 0; dsub < 4; ++dsub) {
      const int d = dsub * 16 + l15;
#pragma unroll
      for (int c = 0; c < 2; ++c) {
        bf16x8v vb = *(const bf16x8v*)((char*)Vt + d * 128 +
                       (((lg * 8 + 32 * c) * 2) ^ ((d & 7) << 4)));
        acc[dsub] = __builtin_amdgcn_mfma_f32_16x16x32_bf16(pa[c], vb, acc[dsub], 0, 0, 0);
      }
    }
  }

  // ---- epilogue: O = acc / l ----
#pragma unroll
  for (int dsub = 0; dsub < 4; ++dsub) {
#pragma unroll
    for (int r = 0; r < 4; ++r) {
      const int qq = q0 + 16 * w + lg * 4 + r;
      const int dd = dsub * 16 + l15;
      Op[(size_t)qq * D + dd] = acc[dsub][r] / lsum[r];
    }
  }
}

extern "C" void kernel_launch(void* const* d_in, const int* in_sizes, int n_in,
                              void* d_out, int out_size, void* d_ws, size_t ws_size,
                              hipStream_t stream) {
  const float* Kg = (const float*)d_in[0];  // key
  const float* Vg = (const float*)d_in[1];  // value
  const float* Qg = (const float*)d_in[2];  // query
  // d_in[3] = mask: deterministically tril -> handled analytically
  float* Og = (float*)d_out;

  const int BH = 4 * 16;
  dim3 grid(BH * (S / BQ));  // 2048 blocks: (bh<<5) | qb
  dim3 block(256);
  attn_fwd<<<grid, block, 0, stream>>>(Kg, Vg, Qg, Og);
}

// Round 5
// 291.772 us; speedup vs baseline: 1.4586x; 1.4586x over previous
//
#include <hip/hip_runtime.h>
#include <hip/hip_bf16.h>

typedef __attribute__((ext_vector_type(4))) float  f32x4;
typedef __attribute__((ext_vector_type(16))) float f32x16;
typedef __attribute__((ext_vector_type(8))) short  bf16x8v;
typedef __attribute__((ext_vector_type(4))) short  bf16x4v;

__device__ __forceinline__ unsigned short f2bf(float x) {
  union { float f; unsigned u; } v; v.f = x;
  unsigned r = v.u + 0x7FFF + ((v.u >> 16) & 1);   // RNE
  return (unsigned short)(r >> 16);
}
__device__ __forceinline__ unsigned pk2(float lo, float hi2) {
  return (unsigned)f2bf(lo) | ((unsigned)f2bf(hi2) << 16);  // -> v_cvt_pk_bf16_f32
}

constexpr int S  = 2048;
constexpr int D  = 64;
constexpr int BQ = 128;   // q-rows per block (4 waves x 32)
constexpr int BK = 64;    // keys per tile

// Swapped-QK^T flash attention, 32x32x16 MFMA.
// Per wave: 32 q-rows, q = q0 + 32*w + (lane&31). Softmax fully in-register.
// PV computed transposed (O^T = V^T P^T) so stats stay per-lane.
__global__ __launch_bounds__(256, 3) void attn_fwd(
    const float* __restrict__ Kg, const float* __restrict__ Vg,
    const float* __restrict__ Qg, float* __restrict__ Og) {
  __shared__ unsigned short Kl[BK * D];  // row = key, XOR-swizzled, 8 KB
  __shared__ unsigned short Vt[D * BK];  // row = d, col = key, XOR-swizzled, 8 KB

  const int tid  = threadIdx.x;
  const int lane = tid & 63;
  const int w    = tid >> 6;        // wave 0..3
  const int l31  = lane & 31;
  const int hi   = lane >> 5;       // 0/1

  // LJF: heavy (late-q) blocks first.
  const int qb = 15 - (int)(blockIdx.x & 15);
  const int bh = blockIdx.x >> 4;   // 0..63
  const int q0 = qb * BQ;

  const size_t base = (size_t)bh * S * D;
  const float* Kp = Kg + base;
  const float* Vp = Vg + base;
  const float* Qp = Qg + base;
  float*       Op = Og + base;

  const int qrow = q0 + w * 32 + l31;   // this lane's q-row (column in S^T)

  // ---- Q as B-frags: lane holds Q[qrow][c*16 + hi*8 + j], j=0..7 ----
  bf16x8v qf[4];
#pragma unroll
  for (int c = 0; c < 4; ++c) {
    const float* src = Qp + (size_t)qrow * D + c * 16 + hi * 8;
    f32x4 a = *(const f32x4*)src;
    f32x4 b = *(const f32x4*)(src + 4);
    bf16x8v f;
    f[0] = f2bf(a[0]); f[1] = f2bf(a[1]); f[2] = f2bf(a[2]); f[3] = f2bf(a[3]);
    f[4] = f2bf(b[0]); f[5] = f2bf(b[1]); f[6] = f2bf(b[2]); f[7] = f2bf(b[3]);
    qf[c] = f;
  }

  f32x16 acc0, acc1;                 // O^T subtiles: d in [0,32) / [32,64)
#pragma unroll
  for (int i = 0; i < 16; ++i) { acc0[i] = 0.f; acc1[i] = 0.f; }
  float mr = -INFINITY, lsum = 0.f;

  const int ktmax      = (q0 + BQ - 1) >> 6;          // block-max tile
  const int wave_ktmax = (q0 + 32 * w + 31) >> 6;     // this wave's need

  for (int kt = 0; kt <= ktmax; ++kt) {
    __syncthreads();  // previous tile consumed
    // ---- stage K tile row-major bf16, XOR swizzle ----
    {
      const int row = tid >> 2;          // key 0..63
      const int cq  = tid & 3;
      const float* ks = Kp + (size_t)(kt * BK + row) * D;
#pragma unroll
      for (int i = 0; i < 4; ++i) {
        const int col = (cq + 4 * i) * 4;
        f32x4 kv = *(const f32x4*)(ks + col);
        bf16x4v kb;
        kb[0] = f2bf(kv[0]); kb[1] = f2bf(kv[1]);
        kb[2] = f2bf(kv[2]); kb[3] = f2bf(kv[3]);
        *(bf16x4v*)((char*)Kl + row * 128 + ((col * 2) ^ ((row & 7) << 4))) = kb;
      }
    }
    // ---- stage V^T via in-register 4x4 transpose, vector stores ----
    {
      const int kgrp = tid >> 4;         // 0..15 -> k0 = 4*kgrp
      const int dgrp = tid & 15;         // 0..15 -> d0 = 4*dgrp
      const int k0 = kgrp * 4, d0 = dgrp * 4;
      const float* vs = Vp + (size_t)(kt * BK + k0) * D + d0;
      f32x4 r0 = *(const f32x4*)(vs);
      f32x4 r1 = *(const f32x4*)(vs + D);
      f32x4 r2 = *(const f32x4*)(vs + 2 * D);
      f32x4 r3 = *(const f32x4*)(vs + 3 * D);
#pragma unroll
      for (int j = 0; j < 4; ++j) {
        const int d = d0 + j;
        bf16x4v tb;
        tb[0] = f2bf(r0[j]); tb[1] = f2bf(r1[j]);
        tb[2] = f2bf(r2[j]); tb[3] = f2bf(r3[j]);
        *(bf16x4v*)((char*)Vt + d * 128 + ((k0 * 2) ^ ((d & 7) << 4))) = tb;
      }
    }
    __syncthreads();

    if (kt <= wave_ktmax) {   // wave-uniform; skipped tiles are fully masked
      const int swz = (l31 & 7) << 4;

      // ---- S^T = K Q^T : s0 = keys [0,32), s1 = keys [32,64) ----
      f32x16 s0, s1;
#pragma unroll
      for (int i = 0; i < 16; ++i) { s0[i] = 0.f; s1[i] = 0.f; }
#pragma unroll
      for (int c = 0; c < 4; ++c) {
        const int kb = c * 32 + hi * 16;
        bf16x8v ka0 = *(const bf16x8v*)((char*)Kl + l31 * 128 + (kb ^ swz));
        s0 = __builtin_amdgcn_mfma_f32_32x32x16_bf16(ka0, qf[c], s0, 0, 0, 0);
        bf16x8v ka1 = *(const bf16x8v*)((char*)Kl + (32 + l31) * 128 + (kb ^ swz));
        s1 = __builtin_amdgcn_mfma_f32_32x32x16_bf16(ka1, qf[c], s1, 0, 0, 0);
      }

      // ---- causal mask + scale; lane owns column q=qrow, rows crow(r,hi) ----
#pragma unroll
      for (int r = 0; r < 16; ++r) {
        const int crow = (r & 3) + 8 * (r >> 2) + 4 * hi;
        const int key0 = kt * BK + crow;
        s0[r] = (key0      <= qrow) ? s0[r] * 0.125f : -INFINITY;
        s1[r] = (key0 + 32 <= qrow) ? s1[r] * 0.125f : -INFINITY;
      }

      // ---- online softmax: local tree + one shfl_xor(32) ----
      float t[16];
#pragma unroll
      for (int r = 0; r < 16; ++r) t[r] = fmaxf(s0[r], s1[r]);
#pragma unroll
      for (int st = 8; st >= 1; st >>= 1)
#pragma unroll
        for (int i = 0; i < 8; ++i)
          if (i < st) t[i] = fmaxf(t[i], t[i + st]);
      float mx = fmaxf(t[0], __shfl_xor(t[0], 32));
      const float mnew = fmaxf(mr, mx);
      const float corr = __expf(mr - mnew);   // first tile: exp(-inf)=0
      mr = mnew;

#pragma unroll
      for (int r = 0; r < 16; ++r) {
        s0[r] = __expf(s0[r] - mnew);
        s1[r] = __expf(s1[r] - mnew);
      }
      float u[16];
#pragma unroll
      for (int r = 0; r < 16; ++r) u[r] = s0[r] + s1[r];
#pragma unroll
      for (int st = 8; st >= 1; st >>= 1)
#pragma unroll
        for (int i = 0; i < 8; ++i)
          if (i < st) u[i] = u[i] + u[i + st];
      float ps = u[0] + __shfl_xor(u[0], 32);
      lsum = lsum * corr + ps;
#pragma unroll
      for (int i = 0; i < 16; ++i) { acc0[i] *= corr; acc1[i] *= corr; }

      // ---- assemble P fragments (bf16) + PV: acc(d) += V^T(d,k) P^T(k,q) ----
#pragma unroll
      for (int c = 0; c < 4; ++c) {
        const int rb = (c & 1) * 8;
        // P source: chunk c<2 from s0 (keys 0-31), else s1
        float p0, p1, p2, p3, p4, p5, p6, p7;
        if (c & 2) {
          p0 = s1[rb+0]; p1 = s1[rb+1]; p2 = s1[rb+2]; p3 = s1[rb+3];
          p4 = s1[rb+4]; p5 = s1[rb+5]; p6 = s1[rb+6]; p7 = s1[rb+7];
        } else {
          p0 = s0[rb+0]; p1 = s0[rb+1]; p2 = s0[rb+2]; p3 = s0[rb+3];
          p4 = s0[rb+4]; p5 = s0[rb+5]; p6 = s0[rb+6]; p7 = s0[rb+7];
        }
        const unsigned a0 = pk2(p0, p1), a1 = pk2(p2, p3);
        const unsigned b0 = pk2(p4, p5), b1 = pk2(p6, p7);
        const unsigned oa0 = (unsigned)__shfl_xor((int)a0, 32);
        const unsigned oa1 = (unsigned)__shfl_xor((int)a1, 32);
        const unsigned ob0 = (unsigned)__shfl_xor((int)b0, 32);
        const unsigned ob1 = (unsigned)__shfl_xor((int)b1, 32);
        union { unsigned u4[4]; bf16x8v v; } pw;
        pw.u4[0] = hi ? ob0 : a0;    // j0,j1
        pw.u4[1] = hi ? ob1 : a1;    // j2,j3
        pw.u4[2] = hi ? b0  : oa0;   // j4,j5
        pw.u4[3] = hi ? b1  : oa1;   // j6,j7
        const int kb = c * 32 + hi * 16;
        bf16x8v v0 = *(const bf16x8v*)((char*)Vt + l31 * 128 + (kb ^ swz));
        acc0 = __builtin_amdgcn_mfma_f32_32x32x16_bf16(v0, pw.v, acc0, 0, 0, 0);
        bf16x8v v1 = *(const bf16x8v*)((char*)Vt + (32 + l31) * 128 + (kb ^ swz));
        acc1 = __builtin_amdgcn_mfma_f32_32x32x16_bf16(v1, pw.v, acc1, 0, 0, 0);
      }
    }
  }

  // ---- epilogue: O[qrow][d] = acc^T / lsum ----
  const float inv = 1.0f / lsum;
#pragma unroll
  for (int mq = 0; mq < 4; ++mq) {
    const int dbase = 8 * mq + 4 * hi;
    f32x4 o0, o1;
#pragma unroll
    for (int i = 0; i < 4; ++i) {
      o0[i] = acc0[4 * mq + i] * inv;
      o1[i] = acc1[4 * mq + i] * inv;
    }
    *(f32x4*)(Op + (size_t)qrow * D + dbase)      = o0;
    *(f32x4*)(Op + (size_t)qrow * D + 32 + dbase) = o1;
  }
}

extern "C" void kernel_launch(void* const* d_in, const int* in_sizes, int n_in,
                              void* d_out, int out_size, void* d_ws, size_t ws_size,
                              hipStream_t stream) {
  const float* Kg = (const float*)d_in[0];  // key
  const float* Vg = (const float*)d_in[1];  // value
  const float* Qg = (const float*)d_in[2];  // query
  // d_in[3] = mask: deterministically tril -> handled analytically
  float* Og = (float*)d_out;

  const int BH = 4 * 16;
  dim3 grid(BH * (S / BQ));   // 1024 blocks: (bh<<4) | qb_rev
  dim3 block(256);
  attn_fwd<<<grid, block, 0, stream>>>(Kg, Vg, Qg, Og);
}

// Round 6
// 255.745 us; speedup vs baseline: 1.6641x; 1.1409x over previous
//
#include <hip/hip_runtime.h>
#include <hip/hip_bf16.h>

typedef __attribute__((ext_vector_type(4))) float  f32x4;
typedef __attribute__((ext_vector_type(16))) float f32x16;
typedef __attribute__((ext_vector_type(8))) short  bf16x8v;
typedef __attribute__((ext_vector_type(4))) short  bf16x4v;

__device__ __forceinline__ unsigned short f2bf(float x) {
  __bf16 h = (__bf16)x;                       // RNE; compiler emits v_cvt_pk
  return __builtin_bit_cast(unsigned short, h);
}
__device__ __forceinline__ unsigned pk2(float lo, float hi2) {
  return (unsigned)f2bf(lo) | ((unsigned)f2bf(hi2) << 16);
}

constexpr int S  = 2048;
constexpr int D  = 64;
constexpr int BQ = 256;   // q-rows per block (8 waves x 32)
constexpr int BK = 64;    // keys per tile
// 0.125 (1/sqrt(64)) * log2(e), folded into exp2-domain softmax
#define KSCALE 0.18033688011112042f

// Swapped-QK^T flash attention, 32x32x16 MFMA, 8 waves.
// Waves 0-3 stage K, waves 4-7 stage V^T (register double-buffered, async).
// Softmax fully in-register (lane owns q-column); PV transposed.
__global__ __launch_bounds__(512, 4) void attn_fwd(
    const float* __restrict__ Kg, const float* __restrict__ Vg,
    const float* __restrict__ Qg, float* __restrict__ Og) {
  __shared__ unsigned short Kl[BK * D];  // row=key, XOR-swizzled, 8 KB
  __shared__ unsigned short Vt[D * BK];  // row=d, col=key, XOR-swizzled, 8 KB

  const int tid  = threadIdx.x;
  const int lane = tid & 63;
  const int w    = tid >> 6;        // wave 0..7
  const int l31  = lane & 31;
  const int hi   = lane >> 5;       // 0/1

  // LJF: heavy (late-q) blocks first.
  const int qb = 7 - (int)(blockIdx.x & 7);
  const int bh = blockIdx.x >> 3;   // 0..63
  const int q0 = qb * BQ;

  const size_t base = (size_t)bh * S * D;
  const float* Kp = Kg + base;
  const float* Vp = Vg + base;
  const float* Qp = Qg + base;
  float*       Op = Og + base;

  const int qrow = q0 + w * 32 + l31;   // this lane's q-row

  // ---- staging role (wave-uniform): tid<256 -> K, else -> V^T ----
  const int  st  = tid & 255;
  const bool isK = tid < 256;
  const int  krow = st >> 2, kcol0 = 16 * (st & 3);      // K: 1 row x 16 cols
  const int  kby0 = kcol0 * 2, kswz = (krow & 7) << 4;
  const int  vk0 = 4 * (st >> 4), vd0 = 4 * (st & 15);   // V: 4x4 microtile

  f32x4 pf0, pf1, pf2, pf3;   // staging double-buffer (registers)

  auto LOAD = [&](int kt) {
    if (isK) {
      const float* p = Kp + (size_t)(kt * BK + krow) * D + kcol0;
      pf0 = *(const f32x4*)(p);      pf1 = *(const f32x4*)(p + 4);
      pf2 = *(const f32x4*)(p + 8);  pf3 = *(const f32x4*)(p + 12);
    } else {
      const float* p = Vp + (size_t)(kt * BK + vk0) * D + vd0;
      pf0 = *(const f32x4*)(p);          pf1 = *(const f32x4*)(p + D);
      pf2 = *(const f32x4*)(p + 2 * D);  pf3 = *(const f32x4*)(p + 3 * D);
    }
  };
  auto WRITE = [&]() {
    if (isK) {
      bf16x8v c0, c1;
      c0[0] = f2bf(pf0[0]); c0[1] = f2bf(pf0[1]); c0[2] = f2bf(pf0[2]); c0[3] = f2bf(pf0[3]);
      c0[4] = f2bf(pf1[0]); c0[5] = f2bf(pf1[1]); c0[6] = f2bf(pf1[2]); c0[7] = f2bf(pf1[3]);
      c1[0] = f2bf(pf2[0]); c1[1] = f2bf(pf2[1]); c1[2] = f2bf(pf2[2]); c1[3] = f2bf(pf2[3]);
      c1[4] = f2bf(pf3[0]); c1[5] = f2bf(pf3[1]); c1[6] = f2bf(pf3[2]); c1[7] = f2bf(pf3[3]);
      *(bf16x8v*)((char*)Kl + krow * 128 + ((kby0)      ^ kswz)) = c0;
      *(bf16x8v*)((char*)Kl + krow * 128 + ((kby0 + 16) ^ kswz)) = c1;
    } else {
#pragma unroll
      for (int j = 0; j < 4; ++j) {
        const int d = vd0 + j;
        bf16x4v tb;
        tb[0] = f2bf(pf0[j]); tb[1] = f2bf(pf1[j]);
        tb[2] = f2bf(pf2[j]); tb[3] = f2bf(pf3[j]);
        *(bf16x4v*)((char*)Vt + d * 128 + ((vk0 * 2) ^ ((d & 7) << 4))) = tb;
      }
    }
  };

  // ---- Q as B-frags: lane holds Q[qrow][c*16 + hi*8 + j], j=0..7 ----
  bf16x8v qf[4];
#pragma unroll
  for (int c = 0; c < 4; ++c) {
    const float* src = Qp + (size_t)qrow * D + c * 16 + hi * 8;
    f32x4 a = *(const f32x4*)src;
    f32x4 b = *(const f32x4*)(src + 4);
    bf16x8v f;
    f[0] = f2bf(a[0]); f[1] = f2bf(a[1]); f[2] = f2bf(a[2]); f[3] = f2bf(a[3]);
    f[4] = f2bf(b[0]); f[5] = f2bf(b[1]); f[6] = f2bf(b[2]); f[7] = f2bf(b[3]);
    qf[c] = f;
  }

  f32x16 acc0, acc1;   // O^T subtiles: d in [0,32) / [32,64)
#pragma unroll
  for (int i = 0; i < 16; ++i) { acc0[i] = 0.f; acc1[i] = 0.f; }
  float mr = -INFINITY, lsum = 0.f;

  const int ktmax   = 4 * qb + 3;            // block's last staged tile
  const int wave_dt = (q0 + 32 * w) >> 6;    // wave's diagonal (= last) tile

  LOAD(0);   // prologue prefetch

  for (int kt = 0; kt <= ktmax; ++kt) {
    __syncthreads();              // previous tile fully consumed
    WRITE();                      // regs -> LDS (tile kt)
    if (kt < ktmax) LOAD(kt + 1); // issue next-tile loads; land during compute
    __syncthreads();              // tile kt ready

    if (kt <= wave_dt) {
      const int swz = (l31 & 7) << 4;

      // ---- S^T = K Q^T (raw scores) ----
      f32x16 s0, s1;
#pragma unroll
      for (int i = 0; i < 16; ++i) { s0[i] = 0.f; s1[i] = 0.f; }
#pragma unroll
      for (int c = 0; c < 4; ++c) {
        const int kb = c * 32 + hi * 16;
        bf16x8v ka0 = *(const bf16x8v*)((char*)Kl + l31 * 128 + (kb ^ swz));
        s0 = __builtin_amdgcn_mfma_f32_32x32x16_bf16(ka0, qf[c], s0, 0, 0, 0);
        bf16x8v ka1 = *(const bf16x8v*)((char*)Kl + (32 + l31) * 128 + (kb ^ swz));
        s1 = __builtin_amdgcn_mfma_f32_32x32x16_bf16(ka1, qf[c], s1, 0, 0, 0);
      }

      // ---- causal mask: only the wave's single diagonal tile needs it ----
      if (kt == wave_dt) {
#pragma unroll
        for (int r = 0; r < 16; ++r) {
          const int crow = (r & 3) + 8 * (r >> 2) + 4 * hi;
          const int key0 = kt * BK + crow;
          if (key0      > qrow) s0[r] = -INFINITY;
          if (key0 + 32 > qrow) s1[r] = -INFINITY;
        }
      }

      // ---- online softmax in exp2 domain (scale folded into KSCALE) ----
      float a0 = fmaxf(s0[0], s1[0]), a1 = fmaxf(s0[1], s1[1]);
      float a2 = fmaxf(s0[2], s1[2]), a3 = fmaxf(s0[3], s1[3]);
#pragma unroll
      for (int r = 4; r < 16; r += 4) {
        a0 = fmaxf(a0, fmaxf(s0[r],     s1[r]));
        a1 = fmaxf(a1, fmaxf(s0[r + 1], s1[r + 1]));
        a2 = fmaxf(a2, fmaxf(s0[r + 2], s1[r + 2]));
        a3 = fmaxf(a3, fmaxf(s0[r + 3], s1[r + 3]));
      }
      float mx = fmaxf(fmaxf(a0, a1), fmaxf(a2, a3));
      mx = fmaxf(mx, __shfl_xor(mx, 32));
      const float mnew = fmaxf(mr, mx);
      const float corr = __builtin_amdgcn_exp2f((mr - mnew) * KSCALE);
      mr = mnew;
      const float nb = mnew * KSCALE;
#pragma unroll
      for (int r = 0; r < 16; ++r) {
        s0[r] = __builtin_amdgcn_exp2f(__builtin_fmaf(s0[r], KSCALE, -nb));
        s1[r] = __builtin_amdgcn_exp2f(__builtin_fmaf(s1[r], KSCALE, -nb));
      }
      float u0 = s0[0] + s1[0], u1 = s0[1] + s1[1];
      float u2 = s0[2] + s1[2], u3 = s0[3] + s1[3];
#pragma unroll
      for (int r = 4; r < 16; r += 4) {
        u0 += s0[r]     + s1[r];
        u1 += s0[r + 1] + s1[r + 1];
        u2 += s0[r + 2] + s1[r + 2];
        u3 += s0[r + 3] + s1[r + 3];
      }
      float ps = (u0 + u1) + (u2 + u3);
      ps += __shfl_xor(ps, 32);
      lsum = lsum * corr + ps;
#pragma unroll
      for (int i = 0; i < 16; ++i) { acc0[i] *= corr; acc1[i] *= corr; }

      // ---- P fragments (bf16) + PV: acc(d) += V^T(d,k) P^T(k,q) ----
#pragma unroll
      for (int c = 0; c < 4; ++c) {
        const int rb = (c & 1) * 8;
        float p0, p1, p2, p3, p4, p5, p6, p7;
        if (c & 2) {
          p0 = s1[rb+0]; p1 = s1[rb+1]; p2 = s1[rb+2]; p3 = s1[rb+3];
          p4 = s1[rb+4]; p5 = s1[rb+5]; p6 = s1[rb+6]; p7 = s1[rb+7];
        } else {
          p0 = s0[rb+0]; p1 = s0[rb+1]; p2 = s0[rb+2]; p3 = s0[rb+3];
          p4 = s0[rb+4]; p5 = s0[rb+5]; p6 = s0[rb+6]; p7 = s0[rb+7];
        }
        const unsigned a0u = pk2(p0, p1), a1u = pk2(p2, p3);
        const unsigned b0u = pk2(p4, p5), b1u = pk2(p6, p7);
        const unsigned oa0 = (unsigned)__shfl_xor((int)a0u, 32);
        const unsigned oa1 = (unsigned)__shfl_xor((int)a1u, 32);
        const unsigned ob0 = (unsigned)__shfl_xor((int)b0u, 32);
        const unsigned ob1 = (unsigned)__shfl_xor((int)b1u, 32);
        union { unsigned u4[4]; bf16x8v v; } pw;
        pw.u4[0] = hi ? ob0 : a0u;   // j0,j1
        pw.u4[1] = hi ? ob1 : a1u;   // j2,j3
        pw.u4[2] = hi ? b0u : oa0;   // j4,j5
        pw.u4[3] = hi ? b1u : oa1;   // j6,j7
        const int kb = c * 32 + hi * 16;
        bf16x8v v0 = *(const bf16x8v*)((char*)Vt + l31 * 128 + (kb ^ swz));
        acc0 = __builtin_amdgcn_mfma_f32_32x32x16_bf16(v0, pw.v, acc0, 0, 0, 0);
        bf16x8v v1 = *(const bf16x8v*)((char*)Vt + (32 + l31) * 128 + (kb ^ swz));
        acc1 = __builtin_amdgcn_mfma_f32_32x32x16_bf16(v1, pw.v, acc1, 0, 0, 0);
      }
    }
  }

  // ---- epilogue: O[qrow][d] = acc^T / lsum ----
  const float inv = 1.0f / lsum;
#pragma unroll
  for (int mq = 0; mq < 4; ++mq) {
    const int dbase = 8 * mq + 4 * hi;
    f32x4 o0, o1;
#pragma unroll
    for (int i = 0; i < 4; ++i) {
      o0[i] = acc0[4 * mq + i] * inv;
      o1[i] = acc1[4 * mq + i] * inv;
    }
    *(f32x4*)(Op + (size_t)qrow * D + dbase)      = o0;
    *(f32x4*)(Op + (size_t)qrow * D + 32 + dbase) = o1;
  }
}

extern "C" void kernel_launch(void* const* d_in, const int* in_sizes, int n_in,
                              void* d_out, int out_size, void* d_ws, size_t ws_size,
                              hipStream_t stream) {
  const float* Kg = (const float*)d_in[0];  // key
  const float* Vg = (const float*)d_in[1];  // value
  const float* Qg = (const float*)d_in[2];  // query
  // d_in[3] = mask: deterministically tril -> handled analytically
  float* Og = (float*)d_out;

  const int BH = 4 * 16;
  dim3 grid(BH * (S / BQ));   // 512 blocks: (bh<<3) | qb_rev
  dim3 block(512);
  attn_fwd<<<grid, block, 0, stream>>>(Kg, Vg, Qg, Og);
}

// Round 10
// 240.258 us; speedup vs baseline: 1.7713x; 1.0645x over previous
//
#include <hip/hip_runtime.h>
#include <hip/hip_bf16.h>

typedef __attribute__((ext_vector_type(4))) float  f32x4;
typedef __attribute__((ext_vector_type(16))) float f32x16;
typedef __attribute__((ext_vector_type(8))) short  bf16x8v;
typedef __attribute__((ext_vector_type(4))) short  bf16x4v;

__device__ __forceinline__ unsigned short f2bf(float x) {
  __bf16 h = (__bf16)x;                       // RNE; compiler emits v_cvt_pk
  return __builtin_bit_cast(unsigned short, h);
}
__device__ __forceinline__ unsigned pk2(float lo, float hi2) {
  return (unsigned)f2bf(lo) | ((unsigned)f2bf(hi2) << 16);
}

constexpr int S  = 2048;
constexpr int D  = 64;
constexpr int BQ = 256;   // q-rows per block (8 waves x 32)
constexpr int BK = 64;    // keys per tile
// 0.125 (1/sqrt(64)) * log2(e), folded into exp2-domain softmax
#define KSCALE 0.18033688011112042f
#define DTHR   40.0f      // defer-max threshold (raw-score units; *KSCALE=7.2 ln)

// Swapped-QK^T flash attention, 32x32x16 MFMA, 8 waves.
// Waves 0-3 stage K, waves 4-7 stage V^T (register double-buffered, async).
// Softmax fully in-register (lane owns q-column); PV transposed.
__global__ __launch_bounds__(512, 4) void attn_fwd(
    const float* __restrict__ Kg, const float* __restrict__ Vg,
    const float* __restrict__ Qg, float* __restrict__ Og) {
  __shared__ unsigned short Kl[BK * D];  // row=key, XOR-swizzled, 8 KB
  __shared__ unsigned short Vt[D * BK];  // row=d, col=key, XOR-swizzled, 8 KB

  const int tid  = threadIdx.x;
  const int lane = tid & 63;
  const int w    = tid >> 6;        // wave 0..7
  const int l31  = lane & 31;
  const int hi   = lane >> 5;       // 0/1

  // Complementary co-residency: XCD round-robin places blocks c and c+256 on
  // the same CU; give them qb and 7-qb so every CU carries 36 tile-units.
  const int idx = (int)blockIdx.x;
  const int bh  = idx >> 3;                          // 0..63
  const int qb  = (idx < 256) ? (7 - (idx & 7)) : (idx & 7);
  const int q0  = qb * BQ;

  const size_t base = (size_t)bh * S * D;
  const float* Kp = Kg + base;
  const float* Vp = Vg + base;
  const float* Qp = Qg + base;
  float*       Op = Og + base;

  const int qrow = q0 + w * 32 + l31;   // this lane's q-row

  // ---- staging role (wave-uniform): tid<256 -> K, else -> V^T ----
  const int  st  = tid & 255;
  const bool isK = tid < 256;
  const int  krow = st >> 2, kcol0 = 16 * (st & 3);      // K: 1 row x 16 cols
  const int  kby0 = kcol0 * 2, kswz = (krow & 7) << 4;
  const int  vk0 = 4 * (st >> 4), vd0 = 4 * (st & 15);   // V: 4x4 microtile

  f32x4 pf0, pf1, pf2, pf3;   // staging double-buffer (registers)

  auto LOAD = [&](int kt) {
    if (isK) {
      const float* p = Kp + (size_t)(kt * BK + krow) * D + kcol0;
      pf0 = *(const f32x4*)(p);      pf1 = *(const f32x4*)(p + 4);
      pf2 = *(const f32x4*)(p + 8);  pf3 = *(const f32x4*)(p + 12);
    } else {
      const float* p = Vp + (size_t)(kt * BK + vk0) * D + vd0;
      pf0 = *(const f32x4*)(p);          pf1 = *(const f32x4*)(p + D);
      pf2 = *(const f32x4*)(p + 2 * D);  pf3 = *(const f32x4*)(p + 3 * D);
    }
  };
  auto WRITE = [&]() {
    if (isK) {
      bf16x8v c0, c1;
      c0[0] = f2bf(pf0[0]); c0[1] = f2bf(pf0[1]); c0[2] = f2bf(pf0[2]); c0[3] = f2bf(pf0[3]);
      c0[4] = f2bf(pf1[0]); c0[5] = f2bf(pf1[1]); c0[6] = f2bf(pf1[2]); c0[7] = f2bf(pf1[3]);
      c1[0] = f2bf(pf2[0]); c1[1] = f2bf(pf2[1]); c1[2] = f2bf(pf2[2]); c1[3] = f2bf(pf2[3]);
      c1[4] = f2bf(pf3[0]); c1[5] = f2bf(pf3[1]); c1[6] = f2bf(pf3[2]); c1[7] = f2bf(pf3[3]);
      *(bf16x8v*)((char*)Kl + krow * 128 + ((kby0)      ^ kswz)) = c0;
      *(bf16x8v*)((char*)Kl + krow * 128 + ((kby0 + 16) ^ kswz)) = c1;
    } else {
#pragma unroll
      for (int j = 0; j < 4; ++j) {
        const int d = vd0 + j;
        bf16x4v tb;
        tb[0] = f2bf(pf0[j]); tb[1] = f2bf(pf1[j]);
        tb[2] = f2bf(pf2[j]); tb[3] = f2bf(pf3[j]);
        *(bf16x4v*)((char*)Vt + d * 128 + ((vk0 * 2) ^ ((d & 7) << 4))) = tb;
      }
    }
  };

  // ---- Q as B-frags: lane holds Q[qrow][c*16 + hi*8 + j], j=0..7 ----
  bf16x8v qf[4];
#pragma unroll
  for (int c = 0; c < 4; ++c) {
    const float* src = Qp + (size_t)qrow * D + c * 16 + hi * 8;
    f32x4 a = *(const f32x4*)src;
    f32x4 b = *(const f32x4*)(src + 4);
    bf16x8v f;
    f[0] = f2bf(a[0]); f[1] = f2bf(a[1]); f[2] = f2bf(a[2]); f[3] = f2bf(a[3]);
    f[4] = f2bf(b[0]); f[5] = f2bf(b[1]); f[6] = f2bf(b[2]); f[7] = f2bf(b[3]);
    qf[c] = f;
  }

  f32x16 acc0, acc1;   // O^T subtiles: d in [0,32) / [32,64)
#pragma unroll
  for (int i = 0; i < 16; ++i) { acc0[i] = 0.f; acc1[i] = 0.f; }
  float mr = -INFINITY, lsum = 0.f;

  const int ktmax   = 4 * qb + 3;            // block's last staged tile
  const int wave_dt = (q0 + 32 * w) >> 6;    // wave's diagonal (= last) tile

  LOAD(0);   // prologue prefetch

  for (int kt = 0; kt <= ktmax; ++kt) {
    __syncthreads();              // previous tile fully consumed
    WRITE();                      // regs -> LDS (tile kt)
    if (kt < ktmax) LOAD(kt + 1); // issue next-tile loads; land during compute
    __syncthreads();              // tile kt ready

    if (kt <= wave_dt) {
      const int swz = (l31 & 7) << 4;

      // ---- S^T = K Q^T (raw scores) ----
      f32x16 s0, s1;
#pragma unroll
      for (int i = 0; i < 16; ++i) { s0[i] = 0.f; s1[i] = 0.f; }
      __builtin_amdgcn_s_setprio(1);
#pragma unroll
      for (int c = 0; c < 4; ++c) {
        const int kb = c * 32 + hi * 16;
        bf16x8v ka0 = *(const bf16x8v*)((char*)Kl + l31 * 128 + (kb ^ swz));
        s0 = __builtin_amdgcn_mfma_f32_32x32x16_bf16(ka0, qf[c], s0, 0, 0, 0);
        bf16x8v ka1 = *(const bf16x8v*)((char*)Kl + (32 + l31) * 128 + (kb ^ swz));
        s1 = __builtin_amdgcn_mfma_f32_32x32x16_bf16(ka1, qf[c], s1, 0, 0, 0);
      }
      __builtin_amdgcn_s_setprio(0);

      // ---- causal mask: only the wave's single diagonal tile needs it ----
      if (kt == wave_dt) {
#pragma unroll
        for (int r = 0; r < 16; ++r) {
          const int crow = (r & 3) + 8 * (r >> 2) + 4 * hi;
          const int key0 = kt * BK + crow;
          if (key0      > qrow) s0[r] = -INFINITY;
          if (key0 + 32 > qrow) s1[r] = -INFINITY;
        }
      }

      // ---- online softmax in exp2 domain (scale folded into KSCALE) ----
      float a0 = fmaxf(s0[0], s1[0]), a1 = fmaxf(s0[1], s1[1]);
      float a2 = fmaxf(s0[2], s1[2]), a3 = fmaxf(s0[3], s1[3]);
#pragma unroll
      for (int r = 4; r < 16; r += 4) {
        a0 = fmaxf(a0, fmaxf(s0[r],     s1[r]));
        a1 = fmaxf(a1, fmaxf(s0[r + 1], s1[r + 1]));
        a2 = fmaxf(a2, fmaxf(s0[r + 2], s1[r + 2]));
        a3 = fmaxf(a3, fmaxf(s0[r + 3], s1[r + 3]));
      }
      float mx = fmaxf(fmaxf(a0, a1), fmaxf(a2, a3));
      mx = fmaxf(mx, __shfl_xor(mx, 32));

      // defer-max (T13): rescale only when the running max grows materially
      if (!__all(mx <= mr + DTHR)) {
        const float mnew = fmaxf(mr, mx);
        const float corr = __builtin_amdgcn_exp2f((mr - mnew) * KSCALE);
        mr = mnew;
        lsum *= corr;
#pragma unroll
        for (int i = 0; i < 16; ++i) { acc0[i] *= corr; acc1[i] *= corr; }
      }
      const float nb = mr * KSCALE;
#pragma unroll
      for (int r = 0; r < 16; ++r) {
        s0[r] = __builtin_amdgcn_exp2f(__builtin_fmaf(s0[r], KSCALE, -nb));
        s1[r] = __builtin_amdgcn_exp2f(__builtin_fmaf(s1[r], KSCALE, -nb));
      }
      float u0 = s0[0] + s1[0], u1 = s0[1] + s1[1];
      float u2 = s0[2] + s1[2], u3 = s0[3] + s1[3];
#pragma unroll
      for (int r = 4; r < 16; r += 4) {
        u0 += s0[r]     + s1[r];
        u1 += s0[r + 1] + s1[r + 1];
        u2 += s0[r + 2] + s1[r + 2];
        u3 += s0[r + 3] + s1[r + 3];
      }
      float ps = (u0 + u1) + (u2 + u3);
      ps += __shfl_xor(ps, 32);
      lsum += ps;

      // ---- P fragments (bf16, shfl_xor+select — R6-verified) + PV ----
#pragma unroll
      for (int c = 0; c < 4; ++c) {
        const int rb = (c & 1) * 8;
        float p0, p1, p2, p3, p4, p5, p6, p7;
        if (c & 2) {
          p0 = s1[rb+0]; p1 = s1[rb+1]; p2 = s1[rb+2]; p3 = s1[rb+3];
          p4 = s1[rb+4]; p5 = s1[rb+5]; p6 = s1[rb+6]; p7 = s1[rb+7];
        } else {
          p0 = s0[rb+0]; p1 = s0[rb+1]; p2 = s0[rb+2]; p3 = s0[rb+3];
          p4 = s0[rb+4]; p5 = s0[rb+5]; p6 = s0[rb+6]; p7 = s0[rb+7];
        }
        const unsigned a0u = pk2(p0, p1), a1u = pk2(p2, p3);
        const unsigned b0u = pk2(p4, p5), b1u = pk2(p6, p7);
        const unsigned oa0 = (unsigned)__shfl_xor((int)a0u, 32);
        const unsigned oa1 = (unsigned)__shfl_xor((int)a1u, 32);
        const unsigned ob0 = (unsigned)__shfl_xor((int)b0u, 32);
        const unsigned ob1 = (unsigned)__shfl_xor((int)b1u, 32);
        union { unsigned u4[4]; bf16x8v v; } pw;
        pw.u4[0] = hi ? ob0 : a0u;   // j0,j1
        pw.u4[1] = hi ? ob1 : a1u;   // j2,j3
        pw.u4[2] = hi ? b0u : oa0;   // j4,j5
        pw.u4[3] = hi ? b1u : oa1;   // j6,j7
        const int kb = c * 32 + hi * 16;
        bf16x8v v0 = *(const bf16x8v*)((char*)Vt + l31 * 128 + (kb ^ swz));
        bf16x8v v1 = *(const bf16x8v*)((char*)Vt + (32 + l31) * 128 + (kb ^ swz));
        __builtin_amdgcn_s_setprio(1);
        acc0 = __builtin_amdgcn_mfma_f32_32x32x16_bf16(v0, pw.v, acc0, 0, 0, 0);
        acc1 = __builtin_amdgcn_mfma_f32_32x32x16_bf16(v1, pw.v, acc1, 0, 0, 0);
        __builtin_amdgcn_s_setprio(0);
      }
    }
  }

  // ---- epilogue: O[qrow][d] = acc^T / lsum ----
  const float inv = 1.0f / lsum;
#pragma unroll
  for (int mq = 0; mq < 4; ++mq) {
    const int dbase = 8 * mq + 4 * hi;
    f32x4 o0, o1;
#pragma unroll
    for (int i = 0; i < 4; ++i) {
      o0[i] = acc0[4 * mq + i] * inv;
      o1[i] = acc1[4 * mq + i] * inv;
    }
    *(f32x4*)(Op + (size_t)qrow * D + dbase)      = o0;
    *(f32x4*)(Op + (size_t)qrow * D + 32 + dbase) = o1;
  }
}

extern "C" void kernel_launch(void* const* d_in, const int* in_sizes, int n_in,
                              void* d_out, int out_size, void* d_ws, size_t ws_size,
                              hipStream_t stream) {
  const float* Kg = (const float*)d_in[0];  // key
  const float* Vg = (const float*)d_in[1];  // value
  const float* Qg = (const float*)d_in[2];  // query
  // d_in[3] = mask: deterministically tril -> handled analytically
  float* Og = (float*)d_out;

  const int BH = 4 * 16;
  dim3 grid(BH * (S / BQ));   // 512 blocks
  dim3 block(512);
  attn_fwd<<<grid, block, 0, stream>>>(Kg, Vg, Qg, Og);
}